// Round 6
// baseline (228.737 us; speedup 1.0000x reference)
//
#include <hip/hip_runtime.h>
#include <hip/hip_bf16.h>

// Problem constants
#define BB    128
#define C_IN  9
#define T0    2048
#define T1    1024      // after pool1
#define T2    512       // after pool2
#define NN    65536     // B * T2 nodes
#define EE    524288    // edges
#define FEAT  32
#define HID   128
#define OUTC  6

__device__ __forceinline__ float bf_lo(unsigned u) { return __uint_as_float(u << 16); }
__device__ __forceinline__ float bf_hi(unsigned u) { return __uint_as_float(u & 0xffff0000u); }
__device__ __forceinline__ unsigned short f2bf(float f) {
    unsigned x = __float_as_uint(f);
    return (unsigned short)((x + 0x7fffu + ((x >> 16) & 1u)) >> 16);   // RNE
}

// ---------------- fast zero of deg_i (runtime fillBuffer took 43us for 256KB) ----------
__global__ __launch_bounds__(256) void k_zero(int4* __restrict__ p) {
    p[blockIdx.x * 256 + threadIdx.x] = make_int4(0, 0, 0, 0);
}

// ---------------- conv1 (LDS-tiled): x [B,9,2048] -> relu -> pool2 -> h1 [B,16,1024] ---
__global__ __launch_bounds__(256) void k_conv1(const float* __restrict__ x,
                                               const float* __restrict__ w,
                                               const float* __restrict__ bias,
                                               float* __restrict__ h1) {
    __shared__ float sx[C_IN][264];
    __shared__ float swt[45 * 16];
    int b   = blockIdx.x >> 3;
    int qt  = blockIdx.x & 7;
    int tid = threadIdx.x;

    const float* xb = x + (size_t)b * C_IN * T0;
    int gbase = qt * 256 - 2;
    #pragma unroll
    for (int c = 0; c < C_IN; ++c)
        for (int i = tid; i < 260; i += 256) {
            int g = gbase + i;
            sx[c][i] = ((unsigned)g < T0) ? xb[c * T0 + g] : 0.f;
        }
    for (int idx = tid; idx < 720; idx += 256) {
        int o = idx & 15, ck = idx >> 4;
        swt[ck * 16 + o] = w[o * 45 + ck];
    }
    __syncthreads();

    int lane = tid & 63;
    int wv   = tid >> 6;
    int o    = lane & 15;
    int slot = lane >> 4;
    int ttl0 = wv * 32 + slot * 8;

    float acc[16];
    #pragma unroll
    for (int i = 0; i < 16; ++i) acc[i] = 0.f;

    #pragma unroll
    for (int c = 0; c < C_IN; ++c) {
        float wt[5];
        #pragma unroll
        for (int k = 0; k < 5; ++k) wt[k] = swt[(c * 5 + k) * 16 + o];
        #pragma unroll
        for (int cb = 0; cb < 2; ++cb) {
            int Pb = 2 * ttl0 + 8 * cb;
            float4 i0 = *(const float4*)&sx[c][Pb];
            float4 i1 = *(const float4*)&sx[c][Pb + 4];
            float4 i2 = *(const float4*)&sx[c][Pb + 8];
            float in[12] = {i0.x,i0.y,i0.z,i0.w, i1.x,i1.y,i1.z,i1.w, i2.x,i2.y,i2.z,i2.w};
            #pragma unroll
            for (int q = 0; q < 8; ++q) {
                float s = acc[cb * 8 + q];
                #pragma unroll
                for (int k = 0; k < 5; ++k) s += wt[k] * in[q + k];
                acc[cb * 8 + q] = s;
            }
        }
    }

    float bi = bias[o];
    float* hp = h1 + (size_t)(b * 16 + o) * T1 + qt * 128 + ttl0;
    #pragma unroll
    for (int cb = 0; cb < 2; ++cb) {
        float4 r;
        r.x = fmaxf(fmaxf(acc[cb*8+0], acc[cb*8+1]) + bi, 0.f);
        r.y = fmaxf(fmaxf(acc[cb*8+2], acc[cb*8+3]) + bi, 0.f);
        r.z = fmaxf(fmaxf(acc[cb*8+4], acc[cb*8+5]) + bi, 0.f);
        r.w = fmaxf(fmaxf(acc[cb*8+6], acc[cb*8+7]) + bi, 0.f);
        *(float4*)(hp + cb * 4) = r;
    }
}

// ---------------- conv2 (LDS-tiled): h1 -> relu -> pool2 -> nodes_s = nodes * dis[n] ----
__global__ __launch_bounds__(256) void k_conv2(const float* __restrict__ h1,
                                               const float* __restrict__ w,
                                               const float* __restrict__ bias,
                                               const float* __restrict__ dis,
                                               float* __restrict__ nodes_s) {
    __shared__ float sh[16][136];
    __shared__ float swt[80 * 32];
    int b   = blockIdx.x >> 3;
    int qt  = blockIdx.x & 7;
    int tid = threadIdx.x;

    const float* hb = h1 + (size_t)b * 16 * T1;
    int gbase = qt * 128 - 2;
    #pragma unroll
    for (int c = 0; c < 16; ++c)
        for (int i = tid; i < 132; i += 256) {
            int g = gbase + i;
            sh[c][i] = ((unsigned)g < T1) ? hb[c * T1 + g] : 0.f;
        }
    for (int idx = tid; idx < 2560; idx += 256) {
        int o = idx & 31, ck = idx >> 5;
        swt[ck * 32 + o] = w[o * 80 + ck];
    }
    __syncthreads();

    int lane = tid & 63;
    int wv   = tid >> 6;
    int o    = lane & 31;
    int slot = lane >> 5;
    int ttl0 = wv * 16 + slot * 8;

    float acc[16];
    #pragma unroll
    for (int i = 0; i < 16; ++i) acc[i] = 0.f;

    #pragma unroll
    for (int c = 0; c < 16; ++c) {
        float wt[5];
        #pragma unroll
        for (int k = 0; k < 5; ++k) wt[k] = swt[(c * 5 + k) * 32 + o];
        #pragma unroll
        for (int cb = 0; cb < 2; ++cb) {
            int Pb = 2 * ttl0 + 8 * cb;
            float4 i0 = *(const float4*)&sh[c][Pb];
            float4 i1 = *(const float4*)&sh[c][Pb + 4];
            float4 i2 = *(const float4*)&sh[c][Pb + 8];
            float in[12] = {i0.x,i0.y,i0.z,i0.w, i1.x,i1.y,i1.z,i1.w, i2.x,i2.y,i2.z,i2.w};
            #pragma unroll
            for (int q = 0; q < 8; ++q) {
                float s = acc[cb * 8 + q];
                #pragma unroll
                for (int k = 0; k < 5; ++k) s += wt[k] * in[q + k];
                acc[cb * 8 + q] = s;
            }
        }
    }

    float bi = bias[o];
    int node0 = b * T2 + qt * 64 + ttl0;
    size_t nbase = (size_t)node0 * FEAT + o;
    #pragma unroll
    for (int cb = 0; cb < 2; ++cb)
        #pragma unroll
        for (int jj = 0; jj < 4; ++jj) {
            float v = fmaxf(fmaxf(acc[cb*8+2*jj], acc[cb*8+2*jj+1]) + bi, 0.f);
            nodes_s[nbase + (size_t)(cb * 4 + jj) * FEAT] = v * dis[node0 + cb * 4 + jj];
        }
}

// ---------------- degree histogram at dst ----------------
__global__ __launch_bounds__(256) void k_deg(const int* __restrict__ ei,
                                             int* __restrict__ deg_i) {
    int e = blockIdx.x * 256 + threadIdx.x;
    if (e < EE) atomicAdd(&deg_i[ei[EE + e]], 1);
}

// ---------------- scan (exclusive prefix) + dis = rsqrt(deg+1), single block -----------
__global__ __launch_bounds__(1024) void k_scan(const int* __restrict__ deg_i,
                                               int* __restrict__ cursor,
                                               float* __restrict__ dis) {
    __shared__ int part[1024];
    int t = threadIdx.x;
    int4 v[16];
    const int4* dp = (const int4*)deg_i + (size_t)t * 16;
    int s = 0;
    #pragma unroll
    for (int i = 0; i < 16; ++i) {
        v[i] = dp[i];
        s += v[i].x + v[i].y + v[i].z + v[i].w;
    }
    part[t] = s;
    __syncthreads();
    for (int off = 1; off < 1024; off <<= 1) {
        int add = 0;
        if (t >= off) add = part[t - off];
        __syncthreads();
        if (t >= off) part[t] += add;
        __syncthreads();
    }
    int run = (t == 0) ? 0 : part[t - 1];
    int4*   cp = (int4*)cursor + (size_t)t * 16;
    float4* fp = (float4*)dis + (size_t)t * 16;
    #pragma unroll
    for (int i = 0; i < 16; ++i) {
        int4 c; float4 f;
        c.x = run; run += v[i].x;
        c.y = run; run += v[i].y;
        c.z = run; run += v[i].z;
        c.w = run; run += v[i].w;
        f.x = rsqrtf((float)v[i].x + 1.f);
        f.y = rsqrtf((float)v[i].y + 1.f);
        f.z = rsqrtf((float)v[i].z + 1.f);
        f.w = rsqrtf((float)v[i].w + 1.f);
        cp[i] = c;
        fp[i] = f;
    }
}

// ---------------- fill CSR ----------------
__global__ __launch_bounds__(256) void k_fill(const int* __restrict__ ei,
                                              int* __restrict__ cursor,
                                              int* __restrict__ csr_src) {
    int e = blockIdx.x * 256 + threadIdx.x;
    if (e >= EE) return;
    int s = ei[e];
    int d = ei[EE + e];
    int pos = atomicAdd(&cursor[d], 1);
    csr_src[pos] = s;
}

// ---------------- gather1 (32-dim, fp32) ----------------
__global__ __launch_bounds__(256) void k_gather1(const float* __restrict__ nodes_s,
                                                 const int* __restrict__ cursor,
                                                 const int* __restrict__ deg_i,
                                                 const int* __restrict__ csr_src,
                                                 const float* __restrict__ dis,
                                                 float* __restrict__ aggN) {
    int t = blockIdx.x * 256 + threadIdx.x;
    int node = t >> 3;                    // 8 lanes per node (float4 each)
    if (node >= NN) return;
    int lane = t & 7;
    int end = cursor[node];
    int beg = end - deg_i[node];
    const float4* xv = (const float4*)nodes_s;
    float4 acc = xv[(size_t)node * 8 + lane];       // self (already * dis[d])
    for (int j = beg; j < end; ++j) {
        int s = csr_src[j];
        float4 v = xv[(size_t)s * 8 + lane];
        acc.x += v.x; acc.y += v.y; acc.z += v.z; acc.w += v.w;
    }
    float dd = dis[node];
    float4 r; r.x = acc.x * dd; r.y = acc.y * dd; r.z = acc.z * dd; r.w = acc.w * dd;
    ((float4*)aggN)[(size_t)node * 8 + lane] = r;
}

// ---------------- gather2 (128-dim, bf16 in / fp32 out) --------------------------------
__global__ __launch_bounds__(256) void k_gather2(const unsigned short* __restrict__ xws2,
                                                 const int* __restrict__ cursor,
                                                 const int* __restrict__ deg_i,
                                                 const int* __restrict__ csr_src,
                                                 const float* __restrict__ dis,
                                                 float* __restrict__ agg) {
    int t = blockIdx.x * 256 + threadIdx.x;
    int node = t >> 4;                    // 16 lanes per node (8 bf16 each)
    if (node >= NN) return;
    int lane = t & 15;
    int end = cursor[node];
    int beg = end - deg_i[node];
    const uint4* xv = (const uint4*)xws2;
    uint4 q = xv[(size_t)node * 16 + lane];
    float a0 = bf_lo(q.x), a1 = bf_hi(q.x), a2 = bf_lo(q.y), a3 = bf_hi(q.y);
    float a4 = bf_lo(q.z), a5 = bf_hi(q.z), a6 = bf_lo(q.w), a7 = bf_hi(q.w);
    for (int j = beg; j < end; ++j) {
        int s = csr_src[j];
        uint4 p = xv[(size_t)s * 16 + lane];
        a0 += bf_lo(p.x); a1 += bf_hi(p.x); a2 += bf_lo(p.y); a3 += bf_hi(p.y);
        a4 += bf_lo(p.z); a5 += bf_hi(p.z); a6 += bf_lo(p.w); a7 += bf_hi(p.w);
    }
    float dd = dis[node];
    float* op = agg + (size_t)node * HID + lane * 8;
    float4 o0, o1;
    o0.x = a0 * dd; o0.y = a1 * dd; o0.z = a2 * dd; o0.w = a3 * dd;
    o1.x = a4 * dd; o1.y = a5 * dd; o1.z = a6 * dd; o1.w = a7 * dd;
    *(float4*)op       = o0;
    *(float4*)(op + 4) = o1;
}

// ---------------- register-tiled GEMM ----------------
template<int K, bool RELU_BIAS, bool SCALE, bool BF16OUT>
__global__ __launch_bounds__(256) void k_gemm(const float* __restrict__ A,
                                              const float* __restrict__ W,     // [K][HID]
                                              const float* __restrict__ bias,
                                              const float* __restrict__ dis,
                                              void* __restrict__ outv) {
    constexpr int KC = 32;
    constexpr int CHUNKS = K / KC;
    __shared__ float sA[2][KC][128 + 4];
    __shared__ float sB[2][KC][128 + 4];
    int tid = threadIdx.x;
    int rowBase = blockIdx.x * 128;
    int tr = tid >> 4;
    int tc = tid & 15;

    float acc[8][8];
    #pragma unroll
    for (int i = 0; i < 8; ++i)
        #pragma unroll
        for (int j = 0; j < 8; ++j) acc[i][j] = 0.f;

    int ar = tid & 127;
    int aq = (tid >> 7) * 4;

    auto stage = [&](int cc, int bb) {
        const float* arow = A + (size_t)(rowBase + ar) * K + cc * KC + aq * 4;
        #pragma unroll
        for (int q = 0; q < 4; ++q) {
            float4 va = *(const float4*)(arow + q * 4);
            if (RELU_BIAS) {
                float4 vb = *(const float4*)(bias + cc * KC + (aq + q) * 4);
                va.x = fmaxf(va.x + vb.x, 0.f);
                va.y = fmaxf(va.y + vb.y, 0.f);
                va.z = fmaxf(va.z + vb.z, 0.f);
                va.w = fmaxf(va.w + vb.w, 0.f);
            }
            int kb = (aq + q) * 4;
            sA[bb][kb + 0][ar] = va.x;
            sA[bb][kb + 1][ar] = va.y;
            sA[bb][kb + 2][ar] = va.z;
            sA[bb][kb + 3][ar] = va.w;
        }
        #pragma unroll
        for (int it = 0; it < 4; ++it) {
            int i = tid + it * 256;
            int k  = i >> 5;
            int c4 = (i & 31) * 4;
            *(float4*)&sB[bb][k][c4] = *(const float4*)(W + (size_t)(cc * KC + k) * HID + c4);
        }
    };

    stage(0, 0);
    __syncthreads();
    for (int cc = 0; cc < CHUNKS; ++cc) {
        if (cc + 1 < CHUNKS) stage(cc + 1, (cc + 1) & 1);
        int bb = cc & 1;
        #pragma unroll 8
        for (int k = 0; k < KC; ++k) {
            float4 a0 = *(const float4*)&sA[bb][k][tr * 8];
            float4 a1 = *(const float4*)&sA[bb][k][tr * 8 + 4];
            float4 b0 = *(const float4*)&sB[bb][k][tc * 8];
            float4 b1 = *(const float4*)&sB[bb][k][tc * 8 + 4];
            float av[8] = {a0.x, a0.y, a0.z, a0.w, a1.x, a1.y, a1.z, a1.w};
            float bv[8] = {b0.x, b0.y, b0.z, b0.w, b1.x, b1.y, b1.z, b1.w};
            #pragma unroll
            for (int i = 0; i < 8; ++i)
                #pragma unroll
                for (int j = 0; j < 8; ++j) acc[i][j] += av[i] * bv[j];
        }
        __syncthreads();
    }

    #pragma unroll
    for (int i = 0; i < 8; ++i) {
        int row = rowBase + tr * 8 + i;
        float d = SCALE ? dis[row] : 1.0f;
        if (BF16OUT) {
            unsigned short us[8];
            #pragma unroll
            for (int j = 0; j < 8; ++j) us[j] = f2bf(acc[i][j] * d);
            uint4 pv;
            pv.x = (unsigned)us[0] | ((unsigned)us[1] << 16);
            pv.y = (unsigned)us[2] | ((unsigned)us[3] << 16);
            pv.z = (unsigned)us[4] | ((unsigned)us[5] << 16);
            pv.w = (unsigned)us[6] | ((unsigned)us[7] << 16);
            *(uint4*)((unsigned short*)outv + (size_t)row * HID + tc * 8) = pv;
        } else {
            float4 o0, o1;
            o0.x = acc[i][0] * d; o0.y = acc[i][1] * d; o0.z = acc[i][2] * d; o0.w = acc[i][3] * d;
            o1.x = acc[i][4] * d; o1.y = acc[i][5] * d; o1.z = acc[i][6] * d; o1.w = acc[i][7] * d;
            float* op = (float*)outv + (size_t)row * HID + tc * 8;
            *(float4*)op       = o0;
            *(float4*)(op + 4) = o1;
        }
    }
}

// ---------------- pool: partial[b][ch][f] = sum_{tt in chunk} relu(agg2+b2) ------------
__global__ __launch_bounds__(128) void k_pool(const float* __restrict__ agg2,
                                              const float* __restrict__ b2,
                                              float* __restrict__ partial) {
    int b  = blockIdx.x >> 2;
    int ch = blockIdx.x & 3;
    int f  = threadIdx.x;
    float bo = b2[f];
    float sum = 0.f;
    const float* basep = agg2 + ((size_t)b * T2 + ch * 128) * HID + f;
    #pragma unroll 4
    for (int tt = 0; tt < 128; ++tt)
        sum += fmaxf(basep[(size_t)tt * HID] + bo, 0.f);
    partial[((size_t)b * 4 + ch) * HID + f] = sum;
}

// ---------------- classifier: out[b][f] = mean @ cls_w + cls_b -------------------------
__global__ __launch_bounds__(256) void k_cls(const float* __restrict__ partial,
                                             const float* __restrict__ clsw,
                                             const float* __restrict__ clsb,
                                             float* __restrict__ out) {
    int gid = blockIdx.x * 256 + threadIdx.x;
    if (gid >= BB * OUTC) return;
    int b = gid / OUTC;
    int f = gid - b * OUTC;
    const float* p = partial + (size_t)b * 4 * HID;
    float acc = 0.f;
    #pragma unroll 8
    for (int k = 0; k < HID; ++k) {
        float pk = p[k] + p[HID + k] + p[2 * HID + k] + p[3 * HID + k];
        acc += pk * clsw[k * OUTC + f];
    }
    out[gid] = acc * (1.0f / (float)T2) + clsb[f];
}

extern "C" void kernel_launch(void* const* d_in, const int* in_sizes, int n_in,
                              void* d_out, int out_size, void* d_ws, size_t ws_size,
                              hipStream_t stream) {
    const float* x    = (const float*)d_in[0];
    const int*   ei   = (const int*)d_in[1];
    const float* c1w  = (const float*)d_in[2];
    const float* c1b  = (const float*)d_in[3];
    const float* c2w  = (const float*)d_in[4];
    const float* c2b  = (const float*)d_in[5];
    const float* g1w  = (const float*)d_in[6];
    const float* g1b  = (const float*)d_in[7];
    const float* g2w  = (const float*)d_in[8];
    const float* g2b  = (const float*)d_in[9];
    const float* clsw = (const float*)d_in[10];
    const float* clsb = (const float*)d_in[11];
    float* out = (float*)d_out;

    float* ws = (float*)d_ws;
    float* agg1     = ws;                        // N*HID fp32 (agg2 overlays)
    float* agg2     = ws;
    float* h1       = ws + 8388608;
    float* nodes_s  = ws + 10485760;
    float* aggN     = ws + 12582912;
    unsigned short* xws2 = (unsigned short*)(ws + 14680064);   // N*HID bf16
    float* dis      = ws + 18874368;
    int* deg_i      = (int*)(ws + 18939904);
    int* cursor     = (int*)(ws + 19005440);
    int* csr_src    = (int*)(ws + 19070976);
    float* partial  = ws + 19595264;             // BB*4*HID floats
    // total 19660800 floats = 78.6 MB

    // CSR build + normalization
    k_zero<<<NN / (4 * 256), 256, 0, stream>>>((int4*)deg_i);
    k_deg <<<EE / 256, 256, 0, stream>>>(ei, deg_i);
    k_scan<<<1, 1024, 0, stream>>>(deg_i, cursor, dis);
    k_fill<<<EE / 256, 256, 0, stream>>>(ei, cursor, csr_src);

    // temporal conv stack
    k_conv1<<<BB * 8, 256, 0, stream>>>(x, c1w, c1b, h1);
    k_conv2<<<BB * 8, 256, 0, stream>>>(h1, c2w, c2b, dis, nodes_s);

    // GCN layer 1: aggregate first (32-dim), then transform
    k_gather1<<<(NN * 8) / 256, 256, 0, stream>>>(nodes_s, cursor, deg_i, csr_src, dis, aggN);
    k_gemm<FEAT, false, false, false><<<NN / 128, 256, 0, stream>>>(aggN, g1w, nullptr, nullptr, agg1);

    // GCN layer 2: xws2 = (relu(agg1+b1) @ W2) * dis  (bf16), then aggregate
    k_gemm<HID, true, true, true><<<NN / 128, 256, 0, stream>>>(agg1, g2w, g1b, dis, xws2);
    k_gather2<<<(NN * 16) / 256, 256, 0, stream>>>(xws2, cursor, deg_i, csr_src, dis, agg2);

    // mean-pool + classifier
    k_pool<<<BB * 4, 128, 0, stream>>>(agg2, g2b, partial);
    k_cls <<<(BB * OUTC + 255) / 256, 256, 0, stream>>>(partial, clsw, clsb, out);
}

// Round 7
// 194.586 us; speedup vs baseline: 1.1755x; 1.1755x over previous
//
#include <hip/hip_runtime.h>
#include <hip/hip_bf16.h>

// Problem constants
#define BB    128
#define C_IN  9
#define T0    2048
#define T1    1024      // after pool1
#define T2    512       // after pool2
#define NN    65536     // B * T2 nodes
#define EE    524288    // edges
#define FEAT  32
#define HID   128
#define OUTC  6

typedef __attribute__((ext_vector_type(8))) short bf16x8;
typedef __attribute__((ext_vector_type(4))) float f32x4;

__device__ __forceinline__ float bf_lo(unsigned u) { return __uint_as_float(u << 16); }
__device__ __forceinline__ float bf_hi(unsigned u) { return __uint_as_float(u & 0xffff0000u); }
__device__ __forceinline__ unsigned short f2bf(float f) {
    unsigned x = __float_as_uint(f);
    return (unsigned short)((x + 0x7fffu + ((x >> 16) & 1u)) >> 16);   // RNE
}

// ---------------- fast zero of deg_i ----------------
__global__ __launch_bounds__(256) void k_zero(int4* __restrict__ p) {
    p[blockIdx.x * 256 + threadIdx.x] = make_int4(0, 0, 0, 0);
}

// ---------------- conv1 (LDS-tiled): x [B,9,2048] -> relu -> pool2 -> h1 [B,16,1024] ---
__global__ __launch_bounds__(256) void k_conv1(const float* __restrict__ x,
                                               const float* __restrict__ w,
                                               const float* __restrict__ bias,
                                               float* __restrict__ h1) {
    __shared__ float sx[C_IN][264];
    __shared__ float swt[45 * 16];
    int b   = blockIdx.x >> 3;
    int qt  = blockIdx.x & 7;
    int tid = threadIdx.x;

    const float* xb = x + (size_t)b * C_IN * T0;
    int gbase = qt * 256 - 2;
    #pragma unroll
    for (int c = 0; c < C_IN; ++c)
        for (int i = tid; i < 260; i += 256) {
            int g = gbase + i;
            sx[c][i] = ((unsigned)g < T0) ? xb[c * T0 + g] : 0.f;
        }
    for (int idx = tid; idx < 720; idx += 256) {
        int o = idx & 15, ck = idx >> 4;
        swt[ck * 16 + o] = w[o * 45 + ck];
    }
    __syncthreads();

    int lane = tid & 63;
    int wv   = tid >> 6;
    int o    = lane & 15;
    int slot = lane >> 4;
    int ttl0 = wv * 32 + slot * 8;

    float acc[16];
    #pragma unroll
    for (int i = 0; i < 16; ++i) acc[i] = 0.f;

    #pragma unroll
    for (int c = 0; c < C_IN; ++c) {
        float wt[5];
        #pragma unroll
        for (int k = 0; k < 5; ++k) wt[k] = swt[(c * 5 + k) * 16 + o];
        #pragma unroll
        for (int cb = 0; cb < 2; ++cb) {
            int Pb = 2 * ttl0 + 8 * cb;
            float4 i0 = *(const float4*)&sx[c][Pb];
            float4 i1 = *(const float4*)&sx[c][Pb + 4];
            float4 i2 = *(const float4*)&sx[c][Pb + 8];
            float in[12] = {i0.x,i0.y,i0.z,i0.w, i1.x,i1.y,i1.z,i1.w, i2.x,i2.y,i2.z,i2.w};
            #pragma unroll
            for (int q = 0; q < 8; ++q) {
                float s = acc[cb * 8 + q];
                #pragma unroll
                for (int k = 0; k < 5; ++k) s += wt[k] * in[q + k];
                acc[cb * 8 + q] = s;
            }
        }
    }

    float bi = bias[o];
    float* hp = h1 + (size_t)(b * 16 + o) * T1 + qt * 128 + ttl0;
    #pragma unroll
    for (int cb = 0; cb < 2; ++cb) {
        float4 r;
        r.x = fmaxf(fmaxf(acc[cb*8+0], acc[cb*8+1]) + bi, 0.f);
        r.y = fmaxf(fmaxf(acc[cb*8+2], acc[cb*8+3]) + bi, 0.f);
        r.z = fmaxf(fmaxf(acc[cb*8+4], acc[cb*8+5]) + bi, 0.f);
        r.w = fmaxf(fmaxf(acc[cb*8+6], acc[cb*8+7]) + bi, 0.f);
        *(float4*)(hp + cb * 4) = r;
    }
}

// ---------------- conv2 (LDS-tiled): h1 -> relu -> pool2 -> nodes_s = nodes * dis[n] ----
__global__ __launch_bounds__(256) void k_conv2(const float* __restrict__ h1,
                                               const float* __restrict__ w,
                                               const float* __restrict__ bias,
                                               const float* __restrict__ dis,
                                               float* __restrict__ nodes_s) {
    __shared__ float sh[16][136];
    __shared__ float swt[80 * 32];
    int b   = blockIdx.x >> 3;
    int qt  = blockIdx.x & 7;
    int tid = threadIdx.x;

    const float* hb = h1 + (size_t)b * 16 * T1;
    int gbase = qt * 128 - 2;
    #pragma unroll
    for (int c = 0; c < 16; ++c)
        for (int i = tid; i < 132; i += 256) {
            int g = gbase + i;
            sh[c][i] = ((unsigned)g < T1) ? hb[c * T1 + g] : 0.f;
        }
    for (int idx = tid; idx < 2560; idx += 256) {
        int o = idx & 31, ck = idx >> 5;
        swt[ck * 32 + o] = w[o * 80 + ck];
    }
    __syncthreads();

    int lane = tid & 63;
    int wv   = tid >> 6;
    int o    = lane & 31;
    int slot = lane >> 5;
    int ttl0 = wv * 16 + slot * 8;

    float acc[16];
    #pragma unroll
    for (int i = 0; i < 16; ++i) acc[i] = 0.f;

    #pragma unroll
    for (int c = 0; c < 16; ++c) {
        float wt[5];
        #pragma unroll
        for (int k = 0; k < 5; ++k) wt[k] = swt[(c * 5 + k) * 32 + o];
        #pragma unroll
        for (int cb = 0; cb < 2; ++cb) {
            int Pb = 2 * ttl0 + 8 * cb;
            float4 i0 = *(const float4*)&sh[c][Pb];
            float4 i1 = *(const float4*)&sh[c][Pb + 4];
            float4 i2 = *(const float4*)&sh[c][Pb + 8];
            float in[12] = {i0.x,i0.y,i0.z,i0.w, i1.x,i1.y,i1.z,i1.w, i2.x,i2.y,i2.z,i2.w};
            #pragma unroll
            for (int q = 0; q < 8; ++q) {
                float s = acc[cb * 8 + q];
                #pragma unroll
                for (int k = 0; k < 5; ++k) s += wt[k] * in[q + k];
                acc[cb * 8 + q] = s;
            }
        }
    }

    float bi = bias[o];
    int node0 = b * T2 + qt * 64 + ttl0;
    size_t nbase = (size_t)node0 * FEAT + o;
    #pragma unroll
    for (int cb = 0; cb < 2; ++cb)
        #pragma unroll
        for (int jj = 0; jj < 4; ++jj) {
            float v = fmaxf(fmaxf(acc[cb*8+2*jj], acc[cb*8+2*jj+1]) + bi, 0.f);
            nodes_s[nbase + (size_t)(cb * 4 + jj) * FEAT] = v * dis[node0 + cb * 4 + jj];
        }
}

// ---------------- degree histogram at dst ----------------
__global__ __launch_bounds__(256) void k_deg(const int* __restrict__ ei,
                                             int* __restrict__ deg_i) {
    int e = blockIdx.x * 256 + threadIdx.x;
    if (e < EE) atomicAdd(&deg_i[ei[EE + e]], 1);
}

// ---------------- scan + dis, single block ----------------
__global__ __launch_bounds__(1024) void k_scan(const int* __restrict__ deg_i,
                                               int* __restrict__ cursor,
                                               float* __restrict__ dis) {
    __shared__ int part[1024];
    int t = threadIdx.x;
    int4 v[16];
    const int4* dp = (const int4*)deg_i + (size_t)t * 16;
    int s = 0;
    #pragma unroll
    for (int i = 0; i < 16; ++i) {
        v[i] = dp[i];
        s += v[i].x + v[i].y + v[i].z + v[i].w;
    }
    part[t] = s;
    __syncthreads();
    for (int off = 1; off < 1024; off <<= 1) {
        int add = 0;
        if (t >= off) add = part[t - off];
        __syncthreads();
        if (t >= off) part[t] += add;
        __syncthreads();
    }
    int run = (t == 0) ? 0 : part[t - 1];
    int4*   cp = (int4*)cursor + (size_t)t * 16;
    float4* fp = (float4*)dis + (size_t)t * 16;
    #pragma unroll
    for (int i = 0; i < 16; ++i) {
        int4 c; float4 f;
        c.x = run; run += v[i].x;
        c.y = run; run += v[i].y;
        c.z = run; run += v[i].z;
        c.w = run; run += v[i].w;
        f.x = rsqrtf((float)v[i].x + 1.f);
        f.y = rsqrtf((float)v[i].y + 1.f);
        f.z = rsqrtf((float)v[i].z + 1.f);
        f.w = rsqrtf((float)v[i].w + 1.f);
        cp[i] = c;
        fp[i] = f;
    }
}

// ---------------- fill CSR ----------------
__global__ __launch_bounds__(256) void k_fill(const int* __restrict__ ei,
                                              int* __restrict__ cursor,
                                              int* __restrict__ csr_src) {
    int e = blockIdx.x * 256 + threadIdx.x;
    if (e >= EE) return;
    int s = ei[e];
    int d = ei[EE + e];
    int pos = atomicAdd(&cursor[d], 1);
    csr_src[pos] = s;
}

// ---------------- gather1 (32-dim, fp32) ----------------
__global__ __launch_bounds__(256) void k_gather1(const float* __restrict__ nodes_s,
                                                 const int* __restrict__ cursor,
                                                 const int* __restrict__ deg_i,
                                                 const int* __restrict__ csr_src,
                                                 const float* __restrict__ dis,
                                                 float* __restrict__ aggN) {
    int t = blockIdx.x * 256 + threadIdx.x;
    int node = t >> 3;
    if (node >= NN) return;
    int lane = t & 7;
    int end = cursor[node];
    int beg = end - deg_i[node];
    const float4* xv = (const float4*)nodes_s;
    float4 acc = xv[(size_t)node * 8 + lane];
    for (int j = beg; j < end; ++j) {
        int s = csr_src[j];
        float4 v = xv[(size_t)s * 8 + lane];
        acc.x += v.x; acc.y += v.y; acc.z += v.z; acc.w += v.w;
    }
    float dd = dis[node];
    float4 r; r.x = acc.x * dd; r.y = acc.y * dd; r.z = acc.z * dd; r.w = acc.w * dd;
    ((float4*)aggN)[(size_t)node * 8 + lane] = r;
}

// ---------------- register-tiled fp32 GEMM (layer 1): agg1 = aggN @ W1 -----------------
template<int K>
__global__ __launch_bounds__(256) void k_gemm(const float* __restrict__ A,
                                              const float* __restrict__ W,     // [K][HID]
                                              float* __restrict__ out) {
    constexpr int KC = 32;
    constexpr int CHUNKS = K / KC;
    __shared__ float sA[2][KC][128 + 4];
    __shared__ float sB[2][KC][128 + 4];
    int tid = threadIdx.x;
    int rowBase = blockIdx.x * 128;
    int tr = tid >> 4;
    int tc = tid & 15;

    float acc[8][8];
    #pragma unroll
    for (int i = 0; i < 8; ++i)
        #pragma unroll
        for (int j = 0; j < 8; ++j) acc[i][j] = 0.f;

    int ar = tid & 127;
    int aq = (tid >> 7) * 4;

    auto stage = [&](int cc, int bb) {
        const float* arow = A + (size_t)(rowBase + ar) * K + cc * KC + aq * 4;
        #pragma unroll
        for (int q = 0; q < 4; ++q) {
            float4 va = *(const float4*)(arow + q * 4);
            int kb = (aq + q) * 4;
            sA[bb][kb + 0][ar] = va.x;
            sA[bb][kb + 1][ar] = va.y;
            sA[bb][kb + 2][ar] = va.z;
            sA[bb][kb + 3][ar] = va.w;
        }
        #pragma unroll
        for (int it = 0; it < 4; ++it) {
            int i = tid + it * 256;
            int k  = i >> 5;
            int c4 = (i & 31) * 4;
            *(float4*)&sB[bb][k][c4] = *(const float4*)(W + (size_t)(cc * KC + k) * HID + c4);
        }
    };

    stage(0, 0);
    __syncthreads();
    for (int cc = 0; cc < CHUNKS; ++cc) {
        if (cc + 1 < CHUNKS) stage(cc + 1, (cc + 1) & 1);
        int bb = cc & 1;
        #pragma unroll 8
        for (int k = 0; k < KC; ++k) {
            float4 a0 = *(const float4*)&sA[bb][k][tr * 8];
            float4 a1 = *(const float4*)&sA[bb][k][tr * 8 + 4];
            float4 b0 = *(const float4*)&sB[bb][k][tc * 8];
            float4 b1 = *(const float4*)&sB[bb][k][tc * 8 + 4];
            float av[8] = {a0.x, a0.y, a0.z, a0.w, a1.x, a1.y, a1.z, a1.w};
            float bv[8] = {b0.x, b0.y, b0.z, b0.w, b1.x, b1.y, b1.z, b1.w};
            #pragma unroll
            for (int i = 0; i < 8; ++i)
                #pragma unroll
                for (int j = 0; j < 8; ++j) acc[i][j] += av[i] * bv[j];
        }
        __syncthreads();
    }

    #pragma unroll
    for (int i = 0; i < 8; ++i) {
        int row = rowBase + tr * 8 + i;
        float* op = out + (size_t)row * HID + tc * 8;
        *(float4*)op       = make_float4(acc[i][0], acc[i][1], acc[i][2], acc[i][3]);
        *(float4*)(op + 4) = make_float4(acc[i][4], acc[i][5], acc[i][6], acc[i][7]);
    }
}

// ---------------- W2 prep: wt[col][k] = bf16(W2[k][col]) -------------------------------
__global__ __launch_bounds__(256) void k_wprep(const float* __restrict__ w2,
                                               unsigned short* __restrict__ wt) {
    int id = blockIdx.x * 256 + threadIdx.x;    // 16384
    int col = id & 127, k = id >> 7;
    wt[col * 128 + k] = f2bf(w2[(size_t)k * 128 + col]);
}

// ---------------- MFMA bf16 GEMM (layer 2): xws2 = bf16((relu(agg1+b1)@W2) * dis) ------
// Block: 128 rows x 128 cols, K=128 staged whole. LDS tiles XOR-swizzled
// (byte ^= (row&7)<<4) to kill the row-major-D=128 16-way bank conflict.
__global__ __launch_bounds__(256) void k_gemm2m(const float* __restrict__ agg1,
                                                const unsigned short* __restrict__ wt,  // [col][k] bf16
                                                const float* __restrict__ b1,
                                                const float* __restrict__ dis,
                                                unsigned short* __restrict__ xws2) {
    __shared__ short sA[128 * 128];   // [row][k] bf16, swizzled
    __shared__ short sW[128 * 128];   // [col][k] bf16, swizzled
    int tid = threadIdx.x;
    int rowBase = blockIdx.x * 128;

    // stage W (already [col][k] bf16): 16B chunks, swizzled
    #pragma unroll
    for (int it = 0; it < 8; ++it) {
        int cr = it * 16 + (tid >> 4);
        int ck = tid & 15;
        uint4 v = *(const uint4*)(wt + cr * 128 + ck * 8);
        *(uint4*)&sA[0] ; // placeholder removed below
        *(uint4*)&sW[cr * 128 + ((ck * 8) ^ ((cr & 7) << 3))] = v;
    }
    // stage A = bf16(relu(agg1 + b1)), swizzled
    #pragma unroll
    for (int it = 0; it < 8; ++it) {
        int r  = it * 16 + (tid >> 4);
        int ck = tid & 15;
        const float* ap = agg1 + (size_t)(rowBase + r) * 128 + ck * 8;
        float4 v0 = *(const float4*)(ap);
        float4 v1 = *(const float4*)(ap + 4);
        float4 bb0 = *(const float4*)(b1 + ck * 8);
        float4 bb1 = *(const float4*)(b1 + ck * 8 + 4);
        unsigned short us[8];
        us[0] = f2bf(fmaxf(v0.x + bb0.x, 0.f));
        us[1] = f2bf(fmaxf(v0.y + bb0.y, 0.f));
        us[2] = f2bf(fmaxf(v0.z + bb0.z, 0.f));
        us[3] = f2bf(fmaxf(v0.w + bb0.w, 0.f));
        us[4] = f2bf(fmaxf(v1.x + bb1.x, 0.f));
        us[5] = f2bf(fmaxf(v1.y + bb1.y, 0.f));
        us[6] = f2bf(fmaxf(v1.z + bb1.z, 0.f));
        us[7] = f2bf(fmaxf(v1.w + bb1.w, 0.f));
        uint4 pv;
        pv.x = (unsigned)us[0] | ((unsigned)us[1] << 16);
        pv.y = (unsigned)us[2] | ((unsigned)us[3] << 16);
        pv.z = (unsigned)us[4] | ((unsigned)us[5] << 16);
        pv.w = (unsigned)us[6] | ((unsigned)us[7] << 16);
        *(uint4*)&sA[r * 128 + ((ck * 8) ^ ((r & 7) << 3))] = pv;
    }
    __syncthreads();

    int lane = tid & 63;
    int wv   = tid >> 6;
    int lrow = lane & 15;
    int kg   = lane >> 4;                // k-group 0..3

    f32x4 zero = {0.f, 0.f, 0.f, 0.f};
    f32x4 acc[2][8];
    #pragma unroll
    for (int rt = 0; rt < 2; ++rt)
        #pragma unroll
        for (int ct = 0; ct < 8; ++ct) acc[rt][ct] = zero;

    #pragma unroll
    for (int ks = 0; ks < 4; ++ks) {
        int kb8 = ks * 4 + kg;           // 8-bf16 chunk index along k
        bf16x8 af[2];
        #pragma unroll
        for (int rt = 0; rt < 2; ++rt) {
            int r = wv * 32 + rt * 16 + lrow;
            af[rt] = *(const bf16x8*)&sA[r * 128 + ((kb8 * 8) ^ ((r & 7) << 3))];
        }
        #pragma unroll
        for (int ct = 0; ct < 8; ++ct) {
            int c = ct * 16 + lrow;
            bf16x8 bfr = *(const bf16x8*)&sW[c * 128 + ((kb8 * 8) ^ ((c & 7) << 3))];
            acc[0][ct] = __builtin_amdgcn_mfma_f32_16x16x32_bf16(af[0], bfr, acc[0][ct], 0, 0, 0);
            acc[1][ct] = __builtin_amdgcn_mfma_f32_16x16x32_bf16(af[1], bfr, acc[1][ct], 0, 0, 0);
        }
    }

    // epilogue: D layout col=lane&15, row=(lane>>4)*4+reg  [verified m89]
    #pragma unroll
    for (int rt = 0; rt < 2; ++rt) {
        int r0 = rowBase + wv * 32 + rt * 16 + kg * 4;
        #pragma unroll
        for (int q = 0; q < 4; ++q) {
            int grow = r0 + q;
            float d = dis[grow];
            unsigned short* op = xws2 + (size_t)grow * HID + lrow;
            #pragma unroll
            for (int ct = 0; ct < 8; ++ct)
                op[ct * 16] = f2bf(acc[rt][ct][q] * d);
        }
    }
}

// ---------------- gather2 + fused pool: partial[blk][f] = sum_nodes relu(agg2+b2) ------
__global__ __launch_bounds__(256) void k_gather2(const unsigned short* __restrict__ xws2,
                                                 const int* __restrict__ cursor,
                                                 const int* __restrict__ deg_i,
                                                 const int* __restrict__ csr_src,
                                                 const float* __restrict__ dis,
                                                 const float* __restrict__ b2,
                                                 float* __restrict__ partial) {
    __shared__ float sred[16][136];
    int t = blockIdx.x * 256 + threadIdx.x;
    int node = t >> 4;                    // 16 lanes per node (8 bf16 each)
    int lane = t & 15;
    int nloc = threadIdx.x >> 4;
    int end = cursor[node];
    int beg = end - deg_i[node];
    const uint4* xv = (const uint4*)xws2;
    uint4 q = xv[(size_t)node * 16 + lane];
    float a0 = bf_lo(q.x), a1 = bf_hi(q.x), a2 = bf_lo(q.y), a3 = bf_hi(q.y);
    float a4 = bf_lo(q.z), a5 = bf_hi(q.z), a6 = bf_lo(q.w), a7 = bf_hi(q.w);
    for (int j = beg; j < end; ++j) {
        int s = csr_src[j];
        uint4 p = xv[(size_t)s * 16 + lane];
        a0 += bf_lo(p.x); a1 += bf_hi(p.x); a2 += bf_lo(p.y); a3 += bf_hi(p.y);
        a4 += bf_lo(p.z); a5 += bf_hi(p.z); a6 += bf_lo(p.w); a7 += bf_hi(p.w);
    }
    float dd = dis[node];
    float4 pb0 = *(const float4*)(b2 + lane * 8);
    float4 pb1 = *(const float4*)(b2 + lane * 8 + 4);
    float* sp = &sred[nloc][lane * 8];
    sp[0] = fmaxf(a0 * dd + pb0.x, 0.f);
    sp[1] = fmaxf(a1 * dd + pb0.y, 0.f);
    sp[2] = fmaxf(a2 * dd + pb0.z, 0.f);
    sp[3] = fmaxf(a3 * dd + pb0.w, 0.f);
    sp[4] = fmaxf(a4 * dd + pb1.x, 0.f);
    sp[5] = fmaxf(a5 * dd + pb1.y, 0.f);
    sp[6] = fmaxf(a6 * dd + pb1.z, 0.f);
    sp[7] = fmaxf(a7 * dd + pb1.w, 0.f);
    __syncthreads();
    int f = threadIdx.x;
    if (f < 128) {
        float s = 0.f;
        #pragma unroll
        for (int n = 0; n < 16; ++n) s += sred[n][f];
        partial[(size_t)blockIdx.x * HID + f] = s;
    }
}

// ---------------- classifier: out[b][f] = mean @ cls_w + cls_b -------------------------
__global__ __launch_bounds__(128) void k_cls(const float* __restrict__ partial,
                                             const float* __restrict__ clsw,
                                             const float* __restrict__ clsb,
                                             float* __restrict__ out) {
    __shared__ float pooled[HID];
    int b = blockIdx.x;
    int f = threadIdx.x;
    const float* p = partial + (size_t)b * 32 * HID + f;
    float s = 0.f;
    #pragma unroll 8
    for (int c = 0; c < 32; ++c) s += p[c * HID];
    pooled[f] = s;
    __syncthreads();
    if (f < OUTC) {
        float acc = 0.f;
        #pragma unroll 8
        for (int k = 0; k < HID; ++k) acc += pooled[k] * clsw[k * OUTC + f];
        out[b * OUTC + f] = acc * (1.0f / (float)T2) + clsb[f];
    }
}

extern "C" void kernel_launch(void* const* d_in, const int* in_sizes, int n_in,
                              void* d_out, int out_size, void* d_ws, size_t ws_size,
                              hipStream_t stream) {
    const float* x    = (const float*)d_in[0];
    const int*   ei   = (const int*)d_in[1];
    const float* c1w  = (const float*)d_in[2];
    const float* c1b  = (const float*)d_in[3];
    const float* c2w  = (const float*)d_in[4];
    const float* c2b  = (const float*)d_in[5];
    const float* g1w  = (const float*)d_in[6];
    const float* g1b  = (const float*)d_in[7];
    const float* g2w  = (const float*)d_in[8];
    const float* g2b  = (const float*)d_in[9];
    const float* clsw = (const float*)d_in[10];
    const float* clsb = (const float*)d_in[11];
    float* out = (float*)d_out;

    float* ws = (float*)d_ws;
    float* agg1     = ws;                                      // N*HID fp32
    float* h1       = ws + 8388608;                            // dead after conv2
    float* partial  = ws + 8388608;                            // overlays h1 (4096*128)
    unsigned short* wt2 = (unsigned short*)(ws + 8912896);     // 16384 bf16, overlays h1
    float* nodes_s  = ws + 10485760;
    float* aggN     = ws + 12582912;
    unsigned short* xws2 = (unsigned short*)(ws + 14680064);   // N*HID bf16
    float* dis      = ws + 18874368;
    int* deg_i      = (int*)(ws + 18939904);
    int* cursor     = (int*)(ws + 19005440);
    int* csr_src    = (int*)(ws + 19070976);

    // CSR build + normalization
    k_zero<<<NN / (4 * 256), 256, 0, stream>>>((int4*)deg_i);
    k_deg <<<EE / 256, 256, 0, stream>>>(ei, deg_i);
    k_scan<<<1, 1024, 0, stream>>>(deg_i, cursor, dis);
    k_fill<<<EE / 256, 256, 0, stream>>>(ei, cursor, csr_src);

    // temporal conv stack
    k_conv1<<<BB * 8, 256, 0, stream>>>(x, c1w, c1b, h1);
    k_conv2<<<BB * 8, 256, 0, stream>>>(h1, c2w, c2b, dis, nodes_s);

    // GCN layer 1: aggregate first (32-dim), then fp32 transform
    k_gather1<<<(NN * 8) / 256, 256, 0, stream>>>(nodes_s, cursor, deg_i, csr_src, dis, aggN);
    k_gemm<FEAT><<<NN / 128, 256, 0, stream>>>(aggN, g1w, agg1);

    // GCN layer 2: MFMA bf16 transform, then aggregate with fused mean-pool partials
    k_wprep<<<64, 256, 0, stream>>>(g2w, wt2);
    k_gemm2m<<<NN / 128, 256, 0, stream>>>(agg1, wt2, g1b, dis, xws2);
    k_gather2<<<(NN * 16) / 256, 256, 0, stream>>>(xws2, cursor, deg_i, csr_src, dis, g2b, partial);

    // classifier
    k_cls<<<BB, 128, 0, stream>>>(partial, clsw, clsb, out);
}

// Round 8
// 193.467 us; speedup vs baseline: 1.1823x; 1.0058x over previous
//
#include <hip/hip_runtime.h>
#include <hip/hip_bf16.h>

// Problem constants
#define BB    128
#define C_IN  9
#define T0    2048
#define T1    1024      // after pool1
#define T2    512       // after pool2
#define NN    65536     // B * T2 nodes
#define EE    524288    // edges
#define FEAT  32
#define HID   128
#define OUTC  6

typedef __attribute__((ext_vector_type(8))) short bf16x8;
typedef __attribute__((ext_vector_type(4))) float f32x4;

__device__ __forceinline__ float bf_lo(unsigned u) { return __uint_as_float(u << 16); }
__device__ __forceinline__ float bf_hi(unsigned u) { return __uint_as_float(u & 0xffff0000u); }
__device__ __forceinline__ unsigned short f2bf(float f) {
    unsigned x = __float_as_uint(f);
    return (unsigned short)((x + 0x7fffu + ((x >> 16) & 1u)) >> 16);   // RNE
}

// ---------------- fast zero of deg_i ----------------
__global__ __launch_bounds__(256) void k_zero(int4* __restrict__ p) {
    p[blockIdx.x * 256 + threadIdx.x] = make_int4(0, 0, 0, 0);
}

// ---------------- conv1 (LDS-tiled): x [B,9,2048] -> relu -> pool2 -> h1 [B,16,1024] ---
__global__ __launch_bounds__(256) void k_conv1(const float* __restrict__ x,
                                               const float* __restrict__ w,
                                               const float* __restrict__ bias,
                                               float* __restrict__ h1) {
    __shared__ float sx[C_IN][264];
    __shared__ float swt[45 * 16];
    int b   = blockIdx.x >> 3;
    int qt  = blockIdx.x & 7;
    int tid = threadIdx.x;

    const float* xb = x + (size_t)b * C_IN * T0;
    int gbase = qt * 256 - 2;
    #pragma unroll
    for (int c = 0; c < C_IN; ++c)
        for (int i = tid; i < 260; i += 256) {
            int g = gbase + i;
            sx[c][i] = ((unsigned)g < T0) ? xb[c * T0 + g] : 0.f;
        }
    for (int idx = tid; idx < 720; idx += 256) {
        int o = idx & 15, ck = idx >> 4;
        swt[ck * 16 + o] = w[o * 45 + ck];
    }
    __syncthreads();

    int lane = tid & 63;
    int wv   = tid >> 6;
    int o    = lane & 15;
    int slot = lane >> 4;
    int ttl0 = wv * 32 + slot * 8;

    float acc[16];
    #pragma unroll
    for (int i = 0; i < 16; ++i) acc[i] = 0.f;

    #pragma unroll
    for (int c = 0; c < C_IN; ++c) {
        float wt[5];
        #pragma unroll
        for (int k = 0; k < 5; ++k) wt[k] = swt[(c * 5 + k) * 16 + o];
        #pragma unroll
        for (int cb = 0; cb < 2; ++cb) {
            int Pb = 2 * ttl0 + 8 * cb;
            float4 i0 = *(const float4*)&sx[c][Pb];
            float4 i1 = *(const float4*)&sx[c][Pb + 4];
            float4 i2 = *(const float4*)&sx[c][Pb + 8];
            float in[12] = {i0.x,i0.y,i0.z,i0.w, i1.x,i1.y,i1.z,i1.w, i2.x,i2.y,i2.z,i2.w};
            #pragma unroll
            for (int q = 0; q < 8; ++q) {
                float s = acc[cb * 8 + q];
                #pragma unroll
                for (int k = 0; k < 5; ++k) s += wt[k] * in[q + k];
                acc[cb * 8 + q] = s;
            }
        }
    }

    float bi = bias[o];
    float* hp = h1 + (size_t)(b * 16 + o) * T1 + qt * 128 + ttl0;
    #pragma unroll
    for (int cb = 0; cb < 2; ++cb) {
        float4 r;
        r.x = fmaxf(fmaxf(acc[cb*8+0], acc[cb*8+1]) + bi, 0.f);
        r.y = fmaxf(fmaxf(acc[cb*8+2], acc[cb*8+3]) + bi, 0.f);
        r.z = fmaxf(fmaxf(acc[cb*8+4], acc[cb*8+5]) + bi, 0.f);
        r.w = fmaxf(fmaxf(acc[cb*8+6], acc[cb*8+7]) + bi, 0.f);
        *(float4*)(hp + cb * 4) = r;
    }
}

// ---------------- conv2 (LDS-tiled): h1 -> relu -> pool2 -> nodes_s = nodes * dis[n] ----
__global__ __launch_bounds__(256) void k_conv2(const float* __restrict__ h1,
                                               const float* __restrict__ w,
                                               const float* __restrict__ bias,
                                               const float* __restrict__ dis,
                                               float* __restrict__ nodes_s) {
    __shared__ float sh[16][136];
    __shared__ float swt[80 * 32];
    int b   = blockIdx.x >> 3;
    int qt  = blockIdx.x & 7;
    int tid = threadIdx.x;

    const float* hb = h1 + (size_t)b * 16 * T1;
    int gbase = qt * 128 - 2;
    #pragma unroll
    for (int c = 0; c < 16; ++c)
        for (int i = tid; i < 132; i += 256) {
            int g = gbase + i;
            sh[c][i] = ((unsigned)g < T1) ? hb[c * T1 + g] : 0.f;
        }
    for (int idx = tid; idx < 2560; idx += 256) {
        int o = idx & 31, ck = idx >> 5;
        swt[ck * 32 + o] = w[o * 80 + ck];
    }
    __syncthreads();

    int lane = tid & 63;
    int wv   = tid >> 6;
    int o    = lane & 31;
    int slot = lane >> 5;
    int ttl0 = wv * 16 + slot * 8;

    float acc[16];
    #pragma unroll
    for (int i = 0; i < 16; ++i) acc[i] = 0.f;

    #pragma unroll
    for (int c = 0; c < 16; ++c) {
        float wt[5];
        #pragma unroll
        for (int k = 0; k < 5; ++k) wt[k] = swt[(c * 5 + k) * 32 + o];
        #pragma unroll
        for (int cb = 0; cb < 2; ++cb) {
            int Pb = 2 * ttl0 + 8 * cb;
            float4 i0 = *(const float4*)&sh[c][Pb];
            float4 i1 = *(const float4*)&sh[c][Pb + 4];
            float4 i2 = *(const float4*)&sh[c][Pb + 8];
            float in[12] = {i0.x,i0.y,i0.z,i0.w, i1.x,i1.y,i1.z,i1.w, i2.x,i2.y,i2.z,i2.w};
            #pragma unroll
            for (int q = 0; q < 8; ++q) {
                float s = acc[cb * 8 + q];
                #pragma unroll
                for (int k = 0; k < 5; ++k) s += wt[k] * in[q + k];
                acc[cb * 8 + q] = s;
            }
        }
    }

    float bi = bias[o];
    int node0 = b * T2 + qt * 64 + ttl0;
    size_t nbase = (size_t)node0 * FEAT + o;
    #pragma unroll
    for (int cb = 0; cb < 2; ++cb)
        #pragma unroll
        for (int jj = 0; jj < 4; ++jj) {
            float v = fmaxf(fmaxf(acc[cb*8+2*jj], acc[cb*8+2*jj+1]) + bi, 0.f);
            nodes_s[nbase + (size_t)(cb * 4 + jj) * FEAT] = v * dis[node0 + cb * 4 + jj];
        }
}

// ---------------- degree histogram at dst ----------------
__global__ __launch_bounds__(256) void k_deg(const int* __restrict__ ei,
                                             int* __restrict__ deg_i) {
    int e = blockIdx.x * 256 + threadIdx.x;
    if (e < EE) atomicAdd(&deg_i[ei[EE + e]], 1);
}

// ---------------- scan + dis, single block ----------------
__global__ __launch_bounds__(1024) void k_scan(const int* __restrict__ deg_i,
                                               int* __restrict__ cursor,
                                               float* __restrict__ dis) {
    __shared__ int part[1024];
    int t = threadIdx.x;
    int4 v[16];
    const int4* dp = (const int4*)deg_i + (size_t)t * 16;
    int s = 0;
    #pragma unroll
    for (int i = 0; i < 16; ++i) {
        v[i] = dp[i];
        s += v[i].x + v[i].y + v[i].z + v[i].w;
    }
    part[t] = s;
    __syncthreads();
    for (int off = 1; off < 1024; off <<= 1) {
        int add = 0;
        if (t >= off) add = part[t - off];
        __syncthreads();
        if (t >= off) part[t] += add;
        __syncthreads();
    }
    int run = (t == 0) ? 0 : part[t - 1];
    int4*   cp = (int4*)cursor + (size_t)t * 16;
    float4* fp = (float4*)dis + (size_t)t * 16;
    #pragma unroll
    for (int i = 0; i < 16; ++i) {
        int4 c; float4 f;
        c.x = run; run += v[i].x;
        c.y = run; run += v[i].y;
        c.z = run; run += v[i].z;
        c.w = run; run += v[i].w;
        f.x = rsqrtf((float)v[i].x + 1.f);
        f.y = rsqrtf((float)v[i].y + 1.f);
        f.z = rsqrtf((float)v[i].z + 1.f);
        f.w = rsqrtf((float)v[i].w + 1.f);
        cp[i] = c;
        fp[i] = f;
    }
}

// ---------------- fill CSR ----------------
__global__ __launch_bounds__(256) void k_fill(const int* __restrict__ ei,
                                              int* __restrict__ cursor,
                                              int* __restrict__ csr_src) {
    int e = blockIdx.x * 256 + threadIdx.x;
    if (e >= EE) return;
    int s = ei[e];
    int d = ei[EE + e];
    int pos = atomicAdd(&cursor[d], 1);
    csr_src[pos] = s;
}

// ---------------- gather1 (32-dim, fp32) ----------------
__global__ __launch_bounds__(256) void k_gather1(const float* __restrict__ nodes_s,
                                                 const int* __restrict__ cursor,
                                                 const int* __restrict__ deg_i,
                                                 const int* __restrict__ csr_src,
                                                 const float* __restrict__ dis,
                                                 float* __restrict__ aggN) {
    int t = blockIdx.x * 256 + threadIdx.x;
    int node = t >> 3;
    if (node >= NN) return;
    int lane = t & 7;
    int end = cursor[node];
    int beg = end - deg_i[node];
    const float4* xv = (const float4*)nodes_s;
    float4 acc = xv[(size_t)node * 8 + lane];
    for (int j = beg; j < end; ++j) {
        int s = csr_src[j];
        float4 v = xv[(size_t)s * 8 + lane];
        acc.x += v.x; acc.y += v.y; acc.z += v.z; acc.w += v.w;
    }
    float dd = dis[node];
    float4 r; r.x = acc.x * dd; r.y = acc.y * dd; r.z = acc.z * dd; r.w = acc.w * dd;
    ((float4*)aggN)[(size_t)node * 8 + lane] = r;
}

// ---------------- W2 prep: wt[col][k] = bf16(W2[k][col]) -------------------------------
__global__ __launch_bounds__(256) void k_wprep(const float* __restrict__ w2,
                                               unsigned short* __restrict__ wt) {
    int id = blockIdx.x * 256 + threadIdx.x;    // 16384
    int col = id & 127, k = id >> 7;
    wt[col * 128 + k] = f2bf(w2[(size_t)k * 128 + col]);
}

// ---------------- fused GCN transform: layer1 fp32 + relu/bias + layer2 MFMA bf16 -------
// xws2[n] = bf16( (relu(aggN[n]@W1 + b1) @ W2) * dis[n] ), per 128-row block.
// LDS: phase-1 tiles (aggN k-major + W1) overlaid by the swizzled bf16 A-tile.
__global__ __launch_bounds__(256) void k_fused(const float* __restrict__ aggN,
                                               const float* __restrict__ w1,     // [32][128]
                                               const unsigned short* __restrict__ wt2, // [col][k] bf16
                                               const float* __restrict__ b1,
                                               const float* __restrict__ dis,
                                               unsigned short* __restrict__ xws2) {
    __shared__ union {
        struct { float an[32][132]; float w1s[32][132]; } p1;   // 33 KB
        short sa[128 * 128];                                    // 32 KB, swizzled bf16 A
    } u;
    __shared__ short sW[128 * 128];   // 32 KB, [col][k] bf16 swizzled

    int tid = threadIdx.x;
    int rowBase = blockIdx.x * 128;

    // stage W2 (bf16 [col][k]) swizzled — independent region
    #pragma unroll
    for (int it = 0; it < 8; ++it) {
        int cr = it * 16 + (tid >> 4);
        int ck = tid & 15;
        uint4 v = *(const uint4*)(wt2 + cr * 128 + ck * 8);
        *(uint4*)&sW[cr * 128 + ((ck * 8) ^ ((cr & 7) << 3))] = v;
    }
    // stage aggN block (k-major) + W1
    {
        int ar = tid & 127;
        int half = tid >> 7;              // 0..1 -> k 0..15 / 16..31
        const float* arow = aggN + (size_t)(rowBase + ar) * FEAT + half * 16;
        #pragma unroll
        for (int q = 0; q < 4; ++q) {
            float4 va = *(const float4*)(arow + q * 4);
            int kb = half * 16 + q * 4;
            u.p1.an[kb + 0][ar] = va.x;
            u.p1.an[kb + 1][ar] = va.y;
            u.p1.an[kb + 2][ar] = va.z;
            u.p1.an[kb + 3][ar] = va.w;
        }
        #pragma unroll
        for (int it = 0; it < 4; ++it) {
            int i = tid + it * 256;       // 0..1023 float4s over [32][128]
            int k  = i >> 5;
            int c4 = (i & 31) * 4;
            *(float4*)&u.p1.w1s[k][c4] = *(const float4*)(w1 + k * HID + c4);
        }
    }
    __syncthreads();

    // ---- layer-1 fp32 GEMM: 8x8 per thread over [128][128] ----
    int tr = tid >> 4, tc = tid & 15;
    float acc[8][8];
    #pragma unroll
    for (int i = 0; i < 8; ++i)
        #pragma unroll
        for (int j = 0; j < 8; ++j) acc[i][j] = 0.f;

    #pragma unroll 8
    for (int k = 0; k < FEAT; ++k) {
        float4 a0 = *(const float4*)&u.p1.an[k][tr * 8];
        float4 a1 = *(const float4*)&u.p1.an[k][tr * 8 + 4];
        float4 b0 = *(const float4*)&u.p1.w1s[k][tc * 8];
        float4 b1v = *(const float4*)&u.p1.w1s[k][tc * 8 + 4];
        float av[8] = {a0.x, a0.y, a0.z, a0.w, a1.x, a1.y, a1.z, a1.w};
        float bv[8] = {b0.x, b0.y, b0.z, b0.w, b1v.x, b1v.y, b1v.z, b1v.w};
        #pragma unroll
        for (int i = 0; i < 8; ++i)
            #pragma unroll
            for (int j = 0; j < 8; ++j) acc[i][j] += av[i] * bv[j];
    }
    __syncthreads();   // phase-1 LDS dead; safe to overlay with sa

    // ---- bias + relu + bf16 pack into swizzled A-tile ----
    {
        float4 bb0 = *(const float4*)(b1 + tc * 8);
        float4 bb1 = *(const float4*)(b1 + tc * 8 + 4);
        float bv[8] = {bb0.x, bb0.y, bb0.z, bb0.w, bb1.x, bb1.y, bb1.z, bb1.w};
        #pragma unroll
        for (int i = 0; i < 8; ++i) {
            int row = tr * 8 + i;
            unsigned short us[8];
            #pragma unroll
            for (int j = 0; j < 8; ++j) us[j] = f2bf(fmaxf(acc[i][j] + bv[j], 0.f));
            uint4 pv;
            pv.x = (unsigned)us[0] | ((unsigned)us[1] << 16);
            pv.y = (unsigned)us[2] | ((unsigned)us[3] << 16);
            pv.z = (unsigned)us[4] | ((unsigned)us[5] << 16);
            pv.w = (unsigned)us[6] | ((unsigned)us[7] << 16);
            *(uint4*)&u.sa[row * 128 + ((tc * 8) ^ ((row & 7) << 3))] = pv;
        }
    }
    __syncthreads();

    // ---- layer-2 MFMA bf16 ----
    int lane = tid & 63;
    int wv   = tid >> 6;
    int lrow = lane & 15;
    int kg   = lane >> 4;                // k-group 0..3

    f32x4 zero = {0.f, 0.f, 0.f, 0.f};
    f32x4 macc[2][8];
    #pragma unroll
    for (int rt = 0; rt < 2; ++rt)
        #pragma unroll
        for (int ct = 0; ct < 8; ++ct) macc[rt][ct] = zero;

    #pragma unroll
    for (int ks = 0; ks < 4; ++ks) {
        int kb8 = ks * 4 + kg;           // 8-bf16 chunk index along k
        bf16x8 af[2];
        #pragma unroll
        for (int rt = 0; rt < 2; ++rt) {
            int r = wv * 32 + rt * 16 + lrow;
            af[rt] = *(const bf16x8*)&u.sa[r * 128 + ((kb8 * 8) ^ ((r & 7) << 3))];
        }
        #pragma unroll
        for (int ct = 0; ct < 8; ++ct) {
            int c = ct * 16 + lrow;
            bf16x8 bfr = *(const bf16x8*)&sW[c * 128 + ((kb8 * 8) ^ ((c & 7) << 3))];
            macc[0][ct] = __builtin_amdgcn_mfma_f32_16x16x32_bf16(af[0], bfr, macc[0][ct], 0, 0, 0);
            macc[1][ct] = __builtin_amdgcn_mfma_f32_16x16x32_bf16(af[1], bfr, macc[1][ct], 0, 0, 0);
        }
    }

    // epilogue: D layout col=lane&15, row=(lane>>4)*4+reg
    #pragma unroll
    for (int rt = 0; rt < 2; ++rt) {
        int r0 = rowBase + wv * 32 + rt * 16 + kg * 4;
        #pragma unroll
        for (int q = 0; q < 4; ++q) {
            int grow = r0 + q;
            float d = dis[grow];
            unsigned short* op = xws2 + (size_t)grow * HID + lrow;
            #pragma unroll
            for (int ct = 0; ct < 8; ++ct)
                op[ct * 16] = f2bf(macc[rt][ct][q] * d);
        }
    }
}

// ---------------- gather2 + fused pool: partial[blk][f] = sum_nodes relu(agg2+b2) ------
__global__ __launch_bounds__(256) void k_gather2(const unsigned short* __restrict__ xws2,
                                                 const int* __restrict__ cursor,
                                                 const int* __restrict__ deg_i,
                                                 const int* __restrict__ csr_src,
                                                 const float* __restrict__ dis,
                                                 const float* __restrict__ b2,
                                                 float* __restrict__ partial) {
    __shared__ float sred[16][136];
    int t = blockIdx.x * 256 + threadIdx.x;
    int node = t >> 4;                    // 16 lanes per node (8 bf16 each)
    int lane = t & 15;
    int nloc = threadIdx.x >> 4;
    int end = cursor[node];
    int beg = end - deg_i[node];
    const uint4* xv = (const uint4*)xws2;
    uint4 q = xv[(size_t)node * 16 + lane];
    float a0 = bf_lo(q.x), a1 = bf_hi(q.x), a2 = bf_lo(q.y), a3 = bf_hi(q.y);
    float a4 = bf_lo(q.z), a5 = bf_hi(q.z), a6 = bf_lo(q.w), a7 = bf_hi(q.w);
    for (int j = beg; j < end; ++j) {
        int s = csr_src[j];
        uint4 p = xv[(size_t)s * 16 + lane];
        a0 += bf_lo(p.x); a1 += bf_hi(p.x); a2 += bf_lo(p.y); a3 += bf_hi(p.y);
        a4 += bf_lo(p.z); a5 += bf_hi(p.z); a6 += bf_lo(p.w); a7 += bf_hi(p.w);
    }
    float dd = dis[node];
    float4 pb0 = *(const float4*)(b2 + lane * 8);
    float4 pb1 = *(const float4*)(b2 + lane * 8 + 4);
    float* sp = &sred[nloc][lane * 8];
    sp[0] = fmaxf(a0 * dd + pb0.x, 0.f);
    sp[1] = fmaxf(a1 * dd + pb0.y, 0.f);
    sp[2] = fmaxf(a2 * dd + pb0.z, 0.f);
    sp[3] = fmaxf(a3 * dd + pb0.w, 0.f);
    sp[4] = fmaxf(a4 * dd + pb1.x, 0.f);
    sp[5] = fmaxf(a5 * dd + pb1.y, 0.f);
    sp[6] = fmaxf(a6 * dd + pb1.z, 0.f);
    sp[7] = fmaxf(a7 * dd + pb1.w, 0.f);
    __syncthreads();
    int f = threadIdx.x;
    if (f < 128) {
        float s = 0.f;
        #pragma unroll
        for (int n = 0; n < 16; ++n) s += sred[n][f];
        partial[(size_t)blockIdx.x * HID + f] = s;
    }
}

// ---------------- classifier: out[b][f] = mean @ cls_w + cls_b -------------------------
__global__ __launch_bounds__(128) void k_cls(const float* __restrict__ partial,
                                             const float* __restrict__ clsw,
                                             const float* __restrict__ clsb,
                                             float* __restrict__ out) {
    __shared__ float pooled[HID];
    int b = blockIdx.x;
    int f = threadIdx.x;
    const float* p = partial + (size_t)b * 32 * HID + f;
    float s = 0.f;
    #pragma unroll 8
    for (int c = 0; c < 32; ++c) s += p[c * HID];
    pooled[f] = s;
    __syncthreads();
    if (f < OUTC) {
        float acc = 0.f;
        #pragma unroll 8
        for (int k = 0; k < HID; ++k) acc += pooled[k] * clsw[k * OUTC + f];
        out[b * OUTC + f] = acc * (1.0f / (float)T2) + clsb[f];
    }
}

extern "C" void kernel_launch(void* const* d_in, const int* in_sizes, int n_in,
                              void* d_out, int out_size, void* d_ws, size_t ws_size,
                              hipStream_t stream) {
    const float* x    = (const float*)d_in[0];
    const int*   ei   = (const int*)d_in[1];
    const float* c1w  = (const float*)d_in[2];
    const float* c1b  = (const float*)d_in[3];
    const float* c2w  = (const float*)d_in[4];
    const float* c2b  = (const float*)d_in[5];
    const float* g1w  = (const float*)d_in[6];
    const float* g1b  = (const float*)d_in[7];
    const float* g2w  = (const float*)d_in[8];
    const float* g2b  = (const float*)d_in[9];
    const float* clsw = (const float*)d_in[10];
    const float* clsb = (const float*)d_in[11];
    float* out = (float*)d_out;

    float* ws = (float*)d_ws;
    float* h1       = ws + 8388608;                            // dead after conv2
    float* partial  = ws + 8388608;                            // overlays h1 (4096*128)
    unsigned short* wt2 = (unsigned short*)(ws + 8912896);     // 16384 bf16, overlays h1
    float* nodes_s  = ws + 10485760;
    float* aggN     = ws + 12582912;
    unsigned short* xws2 = (unsigned short*)(ws + 14680064);   // N*HID bf16
    float* dis      = ws + 18874368;
    int* deg_i      = (int*)(ws + 18939904);
    int* cursor     = (int*)(ws + 19005440);
    int* csr_src    = (int*)(ws + 19070976);

    // CSR build + normalization
    k_zero<<<NN / (4 * 256), 256, 0, stream>>>((int4*)deg_i);
    k_deg <<<EE / 256, 256, 0, stream>>>(ei, deg_i);
    k_scan<<<1, 1024, 0, stream>>>(deg_i, cursor, dis);
    k_fill<<<EE / 256, 256, 0, stream>>>(ei, cursor, csr_src);

    // temporal conv stack
    k_conv1<<<BB * 8, 256, 0, stream>>>(x, c1w, c1b, h1);
    k_conv2<<<BB * 8, 256, 0, stream>>>(h1, c2w, c2b, dis, nodes_s);

    // GCN layer 1 aggregation (32-dim), then fused transform (L1 fp32 + L2 MFMA bf16)
    k_gather1<<<(NN * 8) / 256, 256, 0, stream>>>(nodes_s, cursor, deg_i, csr_src, dis, aggN);
    k_wprep<<<64, 256, 0, stream>>>(g2w, wt2);
    k_fused<<<NN / 128, 256, 0, stream>>>(aggN, g1w, wt2, g1b, dis, xws2);

    // layer-2 aggregation with fused mean-pool partials
    k_gather2<<<(NN * 16) / 256, 256, 0, stream>>>(xws2, cursor, deg_i, csr_src, dis, g2b, partial);

    // classifier
    k_cls<<<BB, 128, 0, stream>>>(partial, clsw, clsb, out);
}